// Round 10
// baseline (57.583 us; speedup 1.0000x reference)
//
#include <hip/hip_runtime.h>
#include <math.h>

#define NN    1000
#define NPAD  1024
#define NTILE 32              /* 32 n-tiles of 32 gaussians                */
#define TPW   8               /* tiles per wave (4 waves split N 4 x 256)  */
#define ITERS 3               /* DIAGNOSTIC x3 repeat of passes B+C        */
#define LOG2E 1.4426950408889634f
#define LN2PI 1.8378770664093453f

typedef float        f32x4  __attribute__((ext_vector_type(4)));
typedef _Float16     f16x8  __attribute__((ext_vector_type(8)));
typedef unsigned int u32x4v __attribute__((ext_vector_type(4)));

static __device__ __forceinline__ float bperm(int byteaddr, float v) {
    return __builtin_bit_cast(float,
        __builtin_amdgcn_ds_bpermute(byteaddr, __builtin_bit_cast(int, v)));
}
static __device__ __forceinline__ float sigmoidf_(float v) {
    return 1.0f / (1.0f + expf(-v));
}
// e = exp2(Kp - u^2 - M), u = p*x + t   (2 FMA + sub + exp)
static __device__ __forceinline__ float ev(float p, float t, float k, float x, float M) {
    float u = fmaf(p, x, t);
    return __builtin_amdgcn_exp2f(fmaf(-u, u, k) - M);
}
static __device__ __forceinline__ unsigned pk2(float a, float b) {
    return __builtin_bit_cast(unsigned, __builtin_amdgcn_cvt_pkrtz(a, b));
}
static __device__ __forceinline__ void opaque1(float& a)  { asm volatile("" : "+v"(a)); }
static __device__ __forceinline__ void opaque4(f32x4& a)  { asm volatile("" : "+v"(a)); }

// ============ fused kernel: 64 px/block (one image row segment) ============
__global__ __launch_bounds__(256, 4) void splat_fused(
    const float* __restrict__ rho, const float* __restrict__ sigma,
    const float* __restrict__ coords, const float* __restrict__ alpha,
    const float* __restrict__ colors, float* __restrict__ out)
{
    __shared__ f32x4  Lp4[NPAD/4], Lt4[NPAD/4], Lk4[NPAD/4];  // 12 KB
    __shared__ u32x4v Lbf[NTILE][4][4];                       //  8 KB [T][col][g]
    __shared__ float  pm[4][64];                              //  1 KB
    __shared__ float  pc[4][64][4];                           //  4 KB

    const int tid  = threadIdx.x;
    const int wave = tid >> 6, lane = tid & 63;
    const int col  = lane & 15, g = lane >> 4;
    const int pxbase = blockIdx.x * 64;
    const float step = 2.0f / 255.0f;
    const float y  = -1.0f + (float)(pxbase >> 8) * step;       // block-uniform
    const float xb = -1.0f + (float)((pxbase & 255) + col) * step;
    const float x0 = xb, x1 = xb + 16.f*step, x2 = xb + 32.f*step, x3 = xb + 48.f*step;

    // ---- phase 0a: derived params (Cholesky log2-domain) + row fold ----
    float* Lp = (float*)Lp4; float* Lt = (float*)Lt4; float* Lk = (float*)Lk4;
    #pragma unroll
    for (int i = 0; i < 4; ++i) {
        int n = tid + 256*i;
        float p, q, r_, u0, v0, K;
        if (n >= NN) { p=q=r_=u0=v0=0.f; K=-1e30f; }   // dummy: contributes 0
        else {
            float sx = tanhf(sigma[2*n]   * 0.5f) + 1e-4f;
            float sy = tanhf(sigma[2*n+1] * 0.5f) + 1e-4f;
            float ra = sigmoidf_(rho[n]) + 1e-6f;
            float cxx = sx*sx + 1e-6f, cyy = sy*sy + 1e-6f;
            float cxy = sx*sy*ra;
            float det = cxx*cyy - cxy*cxy;
            float invdet = 1.0f / det;
            float hl = 0.5f * LOG2E;
            p  = sqrtf(hl * cyy * invdet);
            q  = (-hl * cxy * invdet) / p;
            r_ = sqrtf(hl / cyy);            // exact: b - q^2 = hl/cyy
            float cx = tanhf(coords[2*n])   - 0.5f;
            float cy = tanhf(coords[2*n+1]) - 0.5f;
            u0 = p*cx + q*cy;
            v0 = r_*cy;
            K  = (0.5f * logf(det + 1e-6f) - LN2PI) * LOG2E;
        }
        float t = fmaf(q, y, u0);
        float v = fmaf(r_, y, v0);
        Lp[n] = p; Lt[n] = t; Lk[n] = fmaf(-v, v, K);
    }
    // ---- phase 0b: B-fragments (sigmoid(alpha|rgb) -> f16 pairs) ----
    #pragma unroll
    for (int i = 0; i < 2; ++i) {
        int sid = tid + 256*i;               // 512 slots: T(32) x c(4) x g2(4)
        int T = sid >> 4, c = (sid >> 2) & 3, g2 = sid & 3;
        unsigned w[4] = {0u,0u,0u,0u};
        #pragma unroll
        for (int j = 0; j < 8; ++j) {
            int n = T*32 + g2*8 + j;
            float act = 0.f;
            if (n < NN)
                act = sigmoidf_((c == 0) ? alpha[n] : colors[3*n + c - 1]);
            unsigned short us = __builtin_bit_cast(unsigned short, (_Float16)act);
            w[j>>1] |= (unsigned)us << (16*(j&1));
        }
        Lbf[T][c][g2] = (u32x4v){w[0], w[1], w[2], w[3]};
    }
    __syncthreads();

    // preload this wave's B-fragments (loop-invariant across ITERS)
    u32x4v BfR[TPW];
    #pragma unroll
    for (int t = 0; t < TPW; ++t)
        BfR[t] = (col < 4) ? Lbf[wave*TPW + t][col][g] : (u32x4v){0u,0u,0u,0u};

    const int nbase = wave*256 + g*8;
    const int a16 = ((lane ^ 16) & 63) << 2;     // butterfly across g-groups
    const int a32 = ((lane ^ 32) & 63) << 2;

    f32x4 C0, C1, C2, C3;

    // DIAGNOSTIC: repeat passes B+C ITERS times (bit-identical results).
    // opaque() blocks constant-init CSE; M is re-read from LDS after a
    // barrier each iter, so pass C cannot be CSE'd across iterations.
    for (int it = 0; it < ITERS; ++it) {
        // ---- pass B: per-pixel true max (straight-line, no branches) ----
        float mx0=-3.0e38f, mx1=-3.0e38f, mx2=-3.0e38f, mx3=-3.0e38f;
        opaque1(mx0); opaque1(mx1); opaque1(mx2); opaque1(mx3);
        for (int t = 0; t < TPW; ++t) {
            int q4 = (nbase + t*32) >> 2;
            f32x4 pa = Lp4[q4], pb = Lp4[q4+1];
            f32x4 ta = Lt4[q4], tb = Lt4[q4+1];
            f32x4 ka = Lk4[q4], kb = Lk4[q4+1];
            #pragma unroll
            for (int j = 0; j < 4; ++j) {
                float u;
                u = fmaf(pa[j],x0,ta[j]); mx0 = fmaxf(mx0, fmaf(-u,u,ka[j]));
                u = fmaf(pa[j],x1,ta[j]); mx1 = fmaxf(mx1, fmaf(-u,u,ka[j]));
                u = fmaf(pa[j],x2,ta[j]); mx2 = fmaxf(mx2, fmaf(-u,u,ka[j]));
                u = fmaf(pa[j],x3,ta[j]); mx3 = fmaxf(mx3, fmaf(-u,u,ka[j]));
                u = fmaf(pb[j],x0,tb[j]); mx0 = fmaxf(mx0, fmaf(-u,u,kb[j]));
                u = fmaf(pb[j],x1,tb[j]); mx1 = fmaxf(mx1, fmaf(-u,u,kb[j]));
                u = fmaf(pb[j],x2,tb[j]); mx2 = fmaxf(mx2, fmaf(-u,u,kb[j]));
                u = fmaf(pb[j],x3,tb[j]); mx3 = fmaxf(mx3, fmaf(-u,u,kb[j]));
            }
        }
        mx0 = fmaxf(mx0, bperm(a16, mx0)); mx0 = fmaxf(mx0, bperm(a32, mx0));
        mx1 = fmaxf(mx1, bperm(a16, mx1)); mx1 = fmaxf(mx1, bperm(a32, mx1));
        mx2 = fmaxf(mx2, bperm(a16, mx2)); mx2 = fmaxf(mx2, bperm(a32, mx2));
        mx3 = fmaxf(mx3, bperm(a16, mx3)); mx3 = fmaxf(mx3, bperm(a32, mx3));
        pm[wave][lane] = (g==0) ? mx0 : (g==1) ? mx1 : (g==2) ? mx2 : mx3;
        __syncthreads();
        float M0 = fmaxf(fmaxf(pm[0][col],    pm[1][col]),    fmaxf(pm[2][col],    pm[3][col]));
        float M1 = fmaxf(fmaxf(pm[0][col+16], pm[1][col+16]), fmaxf(pm[2][col+16], pm[3][col+16]));
        float M2 = fmaxf(fmaxf(pm[0][col+32], pm[1][col+32]), fmaxf(pm[2][col+32], pm[3][col+32]));
        float M3 = fmaxf(fmaxf(pm[0][col+48], pm[1][col+48]), fmaxf(pm[2][col+48], pm[3][col+48]));

        // ---- pass C: e = exp2(k - M), MFMA accumulate ----
        C0 = (f32x4){0.f,0.f,0.f,0.f}; C1 = (f32x4){0.f,0.f,0.f,0.f};
        C2 = (f32x4){0.f,0.f,0.f,0.f}; C3 = (f32x4){0.f,0.f,0.f,0.f};
        opaque4(C0); opaque4(C1); opaque4(C2); opaque4(C3);
        for (int t = 0; t < TPW; ++t) {
            int q4 = (nbase + t*32) >> 2;
            f32x4 pa = Lp4[q4], pb = Lp4[q4+1];
            f32x4 ta = Lt4[q4], tb = Lt4[q4+1];
            f32x4 ka = Lk4[q4], kb = Lk4[q4+1];
            f16x8 Bf = __builtin_bit_cast(f16x8, BfR[t]);

            u32x4v W;
            W = (u32x4v){ pk2(ev(pa[0],ta[0],ka[0],x0,M0), ev(pa[1],ta[1],ka[1],x0,M0)),
                          pk2(ev(pa[2],ta[2],ka[2],x0,M0), ev(pa[3],ta[3],ka[3],x0,M0)),
                          pk2(ev(pb[0],tb[0],kb[0],x0,M0), ev(pb[1],tb[1],kb[1],x0,M0)),
                          pk2(ev(pb[2],tb[2],kb[2],x0,M0), ev(pb[3],tb[3],kb[3],x0,M0)) };
            C0 = __builtin_amdgcn_mfma_f32_16x16x32_f16(__builtin_bit_cast(f16x8, W), Bf, C0, 0, 0, 0);
            W = (u32x4v){ pk2(ev(pa[0],ta[0],ka[0],x1,M1), ev(pa[1],ta[1],ka[1],x1,M1)),
                          pk2(ev(pa[2],ta[2],ka[2],x1,M1), ev(pa[3],ta[3],ka[3],x1,M1)),
                          pk2(ev(pb[0],tb[0],kb[0],x1,M1), ev(pb[1],tb[1],kb[1],x1,M1)),
                          pk2(ev(pb[2],tb[2],kb[2],x1,M1), ev(pb[3],tb[3],kb[3],x1,M1)) };
            C1 = __builtin_amdgcn_mfma_f32_16x16x32_f16(__builtin_bit_cast(f16x8, W), Bf, C1, 0, 0, 0);
            W = (u32x4v){ pk2(ev(pa[0],ta[0],ka[0],x2,M2), ev(pa[1],ta[1],ka[1],x2,M2)),
                          pk2(ev(pa[2],ta[2],ka[2],x2,M2), ev(pa[3],ta[3],ka[3],x2,M2)),
                          pk2(ev(pb[0],tb[0],kb[0],x2,M2), ev(pb[1],tb[1],kb[1],x2,M2)),
                          pk2(ev(pb[2],tb[2],kb[2],x2,M2), ev(pb[3],tb[3],kb[3],x2,M2)) };
            C2 = __builtin_amdgcn_mfma_f32_16x16x32_f16(__builtin_bit_cast(f16x8, W), Bf, C2, 0, 0, 0);
            W = (u32x4v){ pk2(ev(pa[0],ta[0],ka[0],x3,M3), ev(pa[1],ta[1],ka[1],x3,M3)),
                          pk2(ev(pa[2],ta[2],ka[2],x3,M3), ev(pa[3],ta[3],ka[3],x3,M3)),
                          pk2(ev(pb[0],tb[0],kb[0],x3,M3), ev(pb[1],tb[1],kb[1],x3,M3)),
                          pk2(ev(pb[2],tb[2],kb[2],x3,M3), ev(pb[3],tb[3],kb[3],x3,M3)) };
            C3 = __builtin_amdgcn_mfma_f32_16x16x32_f16(__builtin_bit_cast(f16x8, W), Bf, C3, 0, 0, 0);
        }
        // keep iterations 0..ITERS-2 live; order pm rewrite after all reads
        asm volatile("" :: "v"(C0), "v"(C1), "v"(C2), "v"(C3));
        __syncthreads();
    }

    // ---- epilogue: cross-wave sum (shared global M -> plain addition) ----
    if (col < 4) {
        #pragma unroll
        for (int i = 0; i < 4; ++i) {        // C layout: col=ch, row=4g+i
            int row = 4*g + i;
            pc[wave][row     ][col] = C0[i];
            pc[wave][row + 16][col] = C1[i];
            pc[wave][row + 32][col] = C2[i];
            pc[wave][row + 48][col] = C3[i];
        }
    }
    __syncthreads();
    if (tid < 64) {
        int px = tid;
        float A = pc[0][px][0] + pc[1][px][0] + pc[2][px][0] + pc[3][px][0];
        float R = pc[0][px][1] + pc[1][px][1] + pc[2][px][1] + pc[3][px][1];
        float G = pc[0][px][2] + pc[1][px][2] + pc[2][px][2] + pc[3][px][2];
        float B = pc[0][px][3] + pc[1][px][3] + pc[2][px][3] + pc[3][px][3];
        float inv = 1.0f / (A + 1e-6f);
        int q = (pxbase + px) * 3;
        out[q] = R*inv; out[q+1] = G*inv; out[q+2] = B*inv;
    }
}

extern "C" void kernel_launch(void* const* d_in, const int* in_sizes, int n_in,
                              void* d_out, int out_size, void* d_ws, size_t ws_size,
                              hipStream_t stream) {
    const float* rho    = (const float*)d_in[0];
    const float* sigma  = (const float*)d_in[1];
    const float* coords = (const float*)d_in[2];
    const float* alpha  = (const float*)d_in[3];
    const float* colors = (const float*)d_in[4];
    float* out = (float*)d_out;   // xy derived analytically (validated r8)

    // 65536 px / 64 px-per-block = 1024 blocks = exactly 4 blocks/CU
    splat_fused<<<1024, 256, 0, stream>>>(rho, sigma, coords, alpha, colors, out);
}

// Round 11
// 27.059 us; speedup vs baseline: 2.1281x; 2.1281x over previous
//
#include <hip/hip_runtime.h>
#include <math.h>

#define NN    1000
#define NPAD  1024
#define NTILE 32              /* 32 n-tiles of 32 gaussians                */
#define TPW   8               /* tiles per wave (4 waves split N 4 x 256)  */
#define LOG2E 1.4426950408889634f
#define LN2PI 1.8378770664093453f

typedef float        f32x4  __attribute__((ext_vector_type(4)));
typedef _Float16     f16x8  __attribute__((ext_vector_type(8)));
typedef unsigned int u32x4v __attribute__((ext_vector_type(4)));

static __device__ __forceinline__ float sigmoidf_(float v) {
    return 1.0f / (1.0f + expf(-v));
}
// e = exp2(kq - u^2), u = p*x + t   (2 FMA + exp2; M pre-folded into kq)
static __device__ __forceinline__ float ev2(float p, float t, float kq, float x) {
    float u = fmaf(p, x, t);
    return __builtin_amdgcn_exp2f(fmaf(-u, u, kq));
}
static __device__ __forceinline__ unsigned pk2(float a, float b) {
    return __builtin_bit_cast(unsigned, __builtin_amdgcn_cvt_pkrtz(a, b));
}

// ============ fused kernel: 64 px/block (one image row segment) ============
// phase 0a: derived params -> LDS (row-folded, kept in regs too)
// phase 0c: per-16px-group analytic max bound M_q (O(N), replaces pass B)
// pass C:   e = exp2(k - M_q) via pre-folded LDS k, f16 MFMA accumulate
__global__ __launch_bounds__(256, 4) void splat_fused(
    const float* __restrict__ rho, const float* __restrict__ sigma,
    const float* __restrict__ coords, const float* __restrict__ alpha,
    const float* __restrict__ colors, float* __restrict__ out)
{
    __shared__ f32x4  Lp4[NPAD/4], Lt4[NPAD/4];   //  8 KB
    __shared__ f32x4  Lkq4[4][NPAD/4];            // 16 KB (k - M_q, 4 variants)
    __shared__ u32x4v Lbf[NTILE][4][4];           //  8 KB [T][col][g]
    __shared__ float  pmw[4][4];                  // [wave][q]
    __shared__ float  pc[4][64][4];               //  4 KB

    const int tid  = threadIdx.x;
    const int wave = tid >> 6, lane = tid & 63;
    const int col  = lane & 15, g = lane >> 4;
    const int pxbase = blockIdx.x * 64;
    const float step = 2.0f / 255.0f;
    const float y   = -1.0f + (float)(pxbase >> 8) * step;      // block-uniform
    const float xg0 = -1.0f + (float)(pxbase & 255) * step;     // group-0 col-0
    const float xb  = xg0 + (float)col * step;
    const float x0 = xb, x1 = xb + 16.f*step, x2 = xb + 32.f*step, x3 = xb + 48.f*step;

    // ---- phase 0a: derived params (Cholesky log2-domain) + row fold ----
    float* Lp = (float*)Lp4; float* Lt = (float*)Lt4;
    float p_[4], t_[4], K_[4];
    #pragma unroll
    for (int i = 0; i < 4; ++i) {
        int n = tid + 256*i;
        float p, q, r_, u0, v0, K;
        if (n >= NN) { p=q=r_=u0=v0=0.f; K=-1e30f; }   // dummy: contributes 0
        else {
            float sx = tanhf(sigma[2*n]   * 0.5f) + 1e-4f;
            float sy = tanhf(sigma[2*n+1] * 0.5f) + 1e-4f;
            float ra = sigmoidf_(rho[n]) + 1e-6f;
            float cxx = sx*sx + 1e-6f, cyy = sy*sy + 1e-6f;
            float cxy = sx*sy*ra;
            float det = cxx*cyy - cxy*cxy;
            float invdet = 1.0f / det;
            float hl = 0.5f * LOG2E;
            p  = sqrtf(hl * cyy * invdet);
            q  = (-hl * cxy * invdet) / p;
            r_ = sqrtf(hl / cyy);            // exact: b - q^2 = hl/cyy
            float cx = tanhf(coords[2*n])   - 0.5f;
            float cy = tanhf(coords[2*n+1]) - 0.5f;
            u0 = p*cx + q*cy;
            v0 = r_*cy;
            K  = (0.5f * logf(det + 1e-6f) - LN2PI) * LOG2E;
        }
        float t = fmaf(q, y, u0);
        float v = fmaf(r_, y, v0);
        p_[i] = p; t_[i] = t; K_[i] = fmaf(-v, v, K);
        Lp[n] = p; Lt[n] = t;
    }
    // ---- phase 0b: B-fragments (sigmoid(alpha|rgb) -> f16 pairs) ----
    #pragma unroll
    for (int i = 0; i < 2; ++i) {
        int sid = tid + 256*i;               // 512 slots: T(32) x c(4) x g2(4)
        int T = sid >> 4, c = (sid >> 2) & 3, g2 = sid & 3;
        unsigned w[4] = {0u,0u,0u,0u};
        #pragma unroll
        for (int j = 0; j < 8; ++j) {
            int n = T*32 + g2*8 + j;
            float act = 0.f;
            if (n < NN)
                act = sigmoidf_((c == 0) ? alpha[n] : colors[3*n + c - 1]);
            unsigned short us = __builtin_bit_cast(unsigned short, (_Float16)act);
            w[j>>1] |= (unsigned)us << (16*(j&1));
        }
        Lbf[T][c][g2] = (u32x4v){w[0], w[1], w[2], w[3]};
    }

    // ---- phase 0c: per-group analytic max bound over this thread's 4 n ----
    // max_{x in [xlo,xhi]} (K - (p*x+t)^2) = K - (ulo*uhi>0 ? min(ulo^2,uhi^2) : 0)
    float gm0=-3e38f, gm1=-3e38f, gm2=-3e38f, gm3=-3e38f;
    #pragma unroll
    for (int i = 0; i < 4; ++i) {
        float p = p_[i], t = t_[i], K = K_[i];
        #pragma unroll
        for (int q = 0; q < 4; ++q) {
            float xlo = xg0 + (float)(16*q) * step;
            float xhi = xlo + 15.f * step;
            float ulo = fmaf(p, xlo, t);
            float uhi = fmaf(p, xhi, t);
            float m2  = fminf(ulo*ulo, uhi*uhi);
            float pen = (ulo*uhi > 0.f) ? m2 : 0.f;
            float km  = K - pen;
            if (q == 0) gm0 = fmaxf(gm0, km);
            else if (q == 1) gm1 = fmaxf(gm1, km);
            else if (q == 2) gm2 = fmaxf(gm2, km);
            else gm3 = fmaxf(gm3, km);
        }
    }
    #pragma unroll
    for (int s = 1; s < 64; s <<= 1) {       // wave butterfly max
        gm0 = fmaxf(gm0, __shfl_xor(gm0, s));
        gm1 = fmaxf(gm1, __shfl_xor(gm1, s));
        gm2 = fmaxf(gm2, __shfl_xor(gm2, s));
        gm3 = fmaxf(gm3, __shfl_xor(gm3, s));
    }
    if (lane == 0) {
        pmw[wave][0]=gm0; pmw[wave][1]=gm1; pmw[wave][2]=gm2; pmw[wave][3]=gm3;
    }
    __syncthreads();

    float Mq[4];
    #pragma unroll
    for (int q = 0; q < 4; ++q)
        Mq[q] = fmaxf(fmaxf(pmw[0][q], pmw[1][q]), fmaxf(pmw[2][q], pmw[3][q]));
    // fold -M_q into k and write the 4 LDS variants
    float* Lkq = (float*)Lkq4;
    #pragma unroll
    for (int i = 0; i < 4; ++i) {
        int n = tid + 256*i;
        #pragma unroll
        for (int q = 0; q < 4; ++q)
            Lkq[q*NPAD + n] = K_[i] - Mq[q];
    }
    __syncthreads();

    // preload this wave's B-fragments
    u32x4v BfR[TPW];
    #pragma unroll
    for (int t = 0; t < TPW; ++t)
        BfR[t] = (col < 4) ? Lbf[wave*TPW + t][col][g] : (u32x4v){0u,0u,0u,0u};

    const int nbase = wave*256 + g*8;

    // ---- pass C: e = exp2(kq - u^2), MFMA accumulate (alpha,r,g,b) ----
    f32x4 C0 = {0.f,0.f,0.f,0.f}, C1 = {0.f,0.f,0.f,0.f};
    f32x4 C2 = {0.f,0.f,0.f,0.f}, C3 = {0.f,0.f,0.f,0.f};
    for (int t = 0; t < TPW; ++t) {
        int q4 = (nbase + t*32) >> 2;
        f32x4 pa  = Lp4[q4],     pb  = Lp4[q4+1];
        f32x4 ta  = Lt4[q4],     tb  = Lt4[q4+1];
        f32x4 k0a = Lkq4[0][q4], k0b = Lkq4[0][q4+1];
        f32x4 k1a = Lkq4[1][q4], k1b = Lkq4[1][q4+1];
        f32x4 k2a = Lkq4[2][q4], k2b = Lkq4[2][q4+1];
        f32x4 k3a = Lkq4[3][q4], k3b = Lkq4[3][q4+1];
        f16x8 Bf = __builtin_bit_cast(f16x8, BfR[t]);

        u32x4v W;
        W = (u32x4v){ pk2(ev2(pa[0],ta[0],k0a[0],x0), ev2(pa[1],ta[1],k0a[1],x0)),
                      pk2(ev2(pa[2],ta[2],k0a[2],x0), ev2(pa[3],ta[3],k0a[3],x0)),
                      pk2(ev2(pb[0],tb[0],k0b[0],x0), ev2(pb[1],tb[1],k0b[1],x0)),
                      pk2(ev2(pb[2],tb[2],k0b[2],x0), ev2(pb[3],tb[3],k0b[3],x0)) };
        C0 = __builtin_amdgcn_mfma_f32_16x16x32_f16(__builtin_bit_cast(f16x8, W), Bf, C0, 0, 0, 0);
        W = (u32x4v){ pk2(ev2(pa[0],ta[0],k1a[0],x1), ev2(pa[1],ta[1],k1a[1],x1)),
                      pk2(ev2(pa[2],ta[2],k1a[2],x1), ev2(pa[3],ta[3],k1a[3],x1)),
                      pk2(ev2(pb[0],tb[0],k1b[0],x1), ev2(pb[1],tb[1],k1b[1],x1)),
                      pk2(ev2(pb[2],tb[2],k1b[2],x1), ev2(pb[3],tb[3],k1b[3],x1)) };
        C1 = __builtin_amdgcn_mfma_f32_16x16x32_f16(__builtin_bit_cast(f16x8, W), Bf, C1, 0, 0, 0);
        W = (u32x4v){ pk2(ev2(pa[0],ta[0],k2a[0],x2), ev2(pa[1],ta[1],k2a[1],x2)),
                      pk2(ev2(pa[2],ta[2],k2a[2],x2), ev2(pa[3],ta[3],k2a[3],x2)),
                      pk2(ev2(pb[0],tb[0],k2b[0],x2), ev2(pb[1],tb[1],k2b[1],x2)),
                      pk2(ev2(pb[2],tb[2],k2b[2],x2), ev2(pb[3],tb[3],k2b[3],x2)) };
        C2 = __builtin_amdgcn_mfma_f32_16x16x32_f16(__builtin_bit_cast(f16x8, W), Bf, C2, 0, 0, 0);
        W = (u32x4v){ pk2(ev2(pa[0],ta[0],k3a[0],x3), ev2(pa[1],ta[1],k3a[1],x3)),
                      pk2(ev2(pa[2],ta[2],k3a[2],x3), ev2(pa[3],ta[3],k3a[3],x3)),
                      pk2(ev2(pb[0],tb[0],k3b[0],x3), ev2(pb[1],tb[1],k3b[1],x3)),
                      pk2(ev2(pb[2],tb[2],k3b[2],x3), ev2(pb[3],tb[3],k3b[3],x3)) };
        C3 = __builtin_amdgcn_mfma_f32_16x16x32_f16(__builtin_bit_cast(f16x8, W), Bf, C3, 0, 0, 0);
    }

    // ---- epilogue: cross-wave sum (all waves share Mq -> plain addition) ----
    if (col < 4) {
        #pragma unroll
        for (int i = 0; i < 4; ++i) {        // C layout: col=ch, row=4g+i
            int row = 4*g + i;
            pc[wave][row     ][col] = C0[i];
            pc[wave][row + 16][col] = C1[i];
            pc[wave][row + 32][col] = C2[i];
            pc[wave][row + 48][col] = C3[i];
        }
    }
    __syncthreads();
    if (tid < 64) {
        int px = tid;
        float A = pc[0][px][0] + pc[1][px][0] + pc[2][px][0] + pc[3][px][0];
        float R = pc[0][px][1] + pc[1][px][1] + pc[2][px][1] + pc[3][px][1];
        float G = pc[0][px][2] + pc[1][px][2] + pc[2][px][2] + pc[3][px][2];
        float B = pc[0][px][3] + pc[1][px][3] + pc[2][px][3] + pc[3][px][3];
        float inv = 1.0f / (A + 1e-6f);
        int q = (pxbase + px) * 3;
        out[q] = R*inv; out[q+1] = G*inv; out[q+2] = B*inv;
    }
}

extern "C" void kernel_launch(void* const* d_in, const int* in_sizes, int n_in,
                              void* d_out, int out_size, void* d_ws, size_t ws_size,
                              hipStream_t stream) {
    const float* rho    = (const float*)d_in[0];
    const float* sigma  = (const float*)d_in[1];
    const float* coords = (const float*)d_in[2];
    const float* alpha  = (const float*)d_in[3];
    const float* colors = (const float*)d_in[4];
    float* out = (float*)d_out;   // xy derived analytically (validated r8)

    // 65536 px / 64 px-per-block = 1024 blocks = exactly 4 blocks/CU
    splat_fused<<<1024, 256, 0, stream>>>(rho, sigma, coords, alpha, colors, out);
}

// Round 12
// 20.561 us; speedup vs baseline: 2.8006x; 1.3160x over previous
//
#include <hip/hip_runtime.h>
#include <math.h>

#define NN    1000
#define NPAD  1024
#define NTILE 32              /* 32 n-tiles of 32 gaussians                 */
#define TPW   8               /* tiles per wave (4 n-chunks of 256)         */
#define LOG2E 1.4426950408889634f
#define LN2PI 1.8378770664093453f

typedef float        f32x4  __attribute__((ext_vector_type(4)));
typedef _Float16     f16x8  __attribute__((ext_vector_type(8)));
typedef unsigned int u32x4v __attribute__((ext_vector_type(4)));

static __device__ __forceinline__ float sigmoidf_(float v) {
    return 1.0f / (1.0f + expf(-v));
}
// e = exp2(kq - u^2), u = p*x + t   (2 FMA + exp2; M pre-folded into kq)
static __device__ __forceinline__ float ev2(float p, float t, float kq, float x) {
    float u = fmaf(p, x, t);
    return __builtin_amdgcn_exp2f(fmaf(-u, u, kq));
}
static __device__ __forceinline__ unsigned pk2(float a, float b) {
    return __builtin_bit_cast(unsigned, __builtin_amdgcn_cvt_pkrtz(a, b));
}

// ============ fused kernel: ONE IMAGE ROW per block (256 px, 16 waves) =====
// phase 0a: 1 gaussian/thread -> params (row-folded) to LDS
// phase 0b: B-fragments (sigmoid alpha|rgb -> f16)
// phase 0c: per-16px-group analytic max bound, chunk-partitioned reduce
// pass C:   e = exp2(kq - u^2) from pre-folded LDS k, f16 MFMA accumulate
__global__ __launch_bounds__(1024, 4) void splat_fused(
    const float* __restrict__ rho, const float* __restrict__ sigma,
    const float* __restrict__ coords, const float* __restrict__ alpha,
    const float* __restrict__ colors, float* __restrict__ out)
{
    __shared__ f32x4  Lp4[NPAD/4], Lt4[NPAD/4], Lk4[NPAD/4];  // 12 KB
    __shared__ f32x4  Lkq4[16][NPAD/4];                       // 64 KB
    __shared__ u32x4v Lbf[NTILE][4][4];                       //  8 KB
    __shared__ float  pm2[64][16];                            //  4 KB
    __shared__ float  pmg[16];
    __shared__ f32x4  pc4[16][64];                            // 16 KB

    const int tid  = threadIdx.x;
    const int wave = tid >> 6, lane = tid & 63;
    const int col  = lane & 15, g = lane >> 4;
    const int nchunk = wave & 3, pxq = wave >> 2;   // n-chunk x pixel-quad
    const int row  = blockIdx.x;
    const float step = 2.0f / 255.0f;
    const float y  = -1.0f + (float)row * step;                 // block-uniform
    const float xb = -1.0f + (float)(64*pxq + col) * step;      // groups 4*pxq+j
    const float x0 = xb, x1 = xb + 16.f*step, x2 = xb + 32.f*step, x3 = xb + 48.f*step;

    // ---- phase 0a: one gaussian per thread (Cholesky log2-domain + fold) ----
    float* Lp = (float*)Lp4; float* Lt = (float*)Lt4; float* Lk = (float*)Lk4;
    {
        const int n = tid;
        float p, q, r_, u0, v0, K;
        if (n >= NN) { p=q=r_=u0=v0=0.f; K=-1e30f; }   // dummy: contributes 0
        else {
            float sx = tanhf(sigma[2*n]   * 0.5f) + 1e-4f;
            float sy = tanhf(sigma[2*n+1] * 0.5f) + 1e-4f;
            float ra = sigmoidf_(rho[n]) + 1e-6f;
            float cxx = sx*sx + 1e-6f, cyy = sy*sy + 1e-6f;
            float cxy = sx*sy*ra;
            float det = cxx*cyy - cxy*cxy;
            float invdet = 1.0f / det;
            float hl = 0.5f * LOG2E;
            p  = sqrtf(hl * cyy * invdet);
            q  = (-hl * cxy * invdet) / p;
            r_ = sqrtf(hl / cyy);            // exact: b - q^2 = hl/cyy
            float cx = tanhf(coords[2*n])   - 0.5f;
            float cy = tanhf(coords[2*n+1]) - 0.5f;
            u0 = p*cx + q*cy;
            v0 = r_*cy;
            K  = (0.5f * logf(det + 1e-6f) - LN2PI) * LOG2E;
        }
        float t = fmaf(q, y, u0);
        float v = fmaf(r_, y, v0);
        Lp[tid] = p; Lt[tid] = t; Lk[tid] = fmaf(-v, v, K);
    }
    // ---- phase 0b: B-fragments, one slot per thread (tid < 512) ----
    if (tid < 512) {                         // slot: T(32) x c(4) x g2(4)
        int T = tid >> 4, c = (tid >> 2) & 3, g2 = tid & 3;
        unsigned w[4] = {0u,0u,0u,0u};
        #pragma unroll
        for (int j = 0; j < 8; ++j) {
            int n = T*32 + g2*8 + j;
            float act = 0.f;
            if (n < NN)
                act = sigmoidf_((c == 0) ? alpha[n] : colors[3*n + c - 1]);
            unsigned short us = __builtin_bit_cast(unsigned short, (_Float16)act);
            w[j>>1] |= (unsigned)us << (16*(j&1));
        }
        Lbf[T][c][g2] = (u32x4v){w[0], w[1], w[2], w[3]};
    }
    __syncthreads();

    // ---- phase 0c: analytic group-max. thread = (16-g chunk) x (16px group) ----
    // max_{x in [xlo,xhi]} (K - (p*x+t)^2) = K - (ulo*uhi>0 ? min(ulo^2,uhi^2) : 0)
    {
        const int q16 = tid & 15, chunk = tid >> 4;
        const float xlo = -1.0f + (float)(16*q16) * step;
        const float xhi = xlo + 15.f*step;
        const int nb = chunk * 16;
        float mx = -3.0e38f;
        #pragma unroll
        for (int i = 0; i < 16; ++i) {
            float p = Lp[nb+i], t = Lt[nb+i], Kp = Lk[nb+i];
            float ulo = fmaf(p, xlo, t);
            float uhi = fmaf(p, xhi, t);
            float pen = (ulo*uhi > 0.f) ? fminf(ulo*ulo, uhi*uhi) : 0.f;
            mx = fmaxf(mx, Kp - pen);
        }
        pm2[chunk][q16] = mx;
    }
    __syncthreads();
    if (tid < 16) {                          // stage 2: 64 partials -> global
        float M = -3.0e38f;
        #pragma unroll
        for (int j = 0; j < 64; ++j) M = fmaxf(M, pm2[j][tid]);
        pmg[tid] = M;
    }
    __syncthreads();
    // fold -M_q into k: 16 LDS variants (own gaussian)
    {
        float Kp = Lk[tid];
        float* Lkq = (float*)Lkq4;
        #pragma unroll
        for (int q = 0; q < 16; ++q)
            Lkq[q*NPAD + tid] = Kp - pmg[q];
    }
    // preload this wave's B-fragments (n-chunk owns tiles nchunk*8 .. +7)
    u32x4v BfR[TPW];
    #pragma unroll
    for (int t = 0; t < TPW; ++t)
        BfR[t] = (col < 4) ? Lbf[nchunk*TPW + t][col][g] : (u32x4v){0u,0u,0u,0u};
    __syncthreads();

    const int nbase = nchunk*256 + g*8;
    const int G0 = pxq * 4;

    // ---- pass C: e = exp2(kq - u^2), MFMA accumulate (alpha,r,g,b) ----
    f32x4 C0 = {0.f,0.f,0.f,0.f}, C1 = {0.f,0.f,0.f,0.f};
    f32x4 C2 = {0.f,0.f,0.f,0.f}, C3 = {0.f,0.f,0.f,0.f};
    for (int t = 0; t < TPW; ++t) {
        int q4 = (nbase + t*32) >> 2;
        f32x4 pa  = Lp4[q4],        pb  = Lp4[q4+1];
        f32x4 ta  = Lt4[q4],        tb  = Lt4[q4+1];
        f32x4 k0a = Lkq4[G0+0][q4], k0b = Lkq4[G0+0][q4+1];
        f32x4 k1a = Lkq4[G0+1][q4], k1b = Lkq4[G0+1][q4+1];
        f32x4 k2a = Lkq4[G0+2][q4], k2b = Lkq4[G0+2][q4+1];
        f32x4 k3a = Lkq4[G0+3][q4], k3b = Lkq4[G0+3][q4+1];
        f16x8 Bf = __builtin_bit_cast(f16x8, BfR[t]);

        u32x4v W;
        W = (u32x4v){ pk2(ev2(pa[0],ta[0],k0a[0],x0), ev2(pa[1],ta[1],k0a[1],x0)),
                      pk2(ev2(pa[2],ta[2],k0a[2],x0), ev2(pa[3],ta[3],k0a[3],x0)),
                      pk2(ev2(pb[0],tb[0],k0b[0],x0), ev2(pb[1],tb[1],k0b[1],x0)),
                      pk2(ev2(pb[2],tb[2],k0b[2],x0), ev2(pb[3],tb[3],k0b[3],x0)) };
        C0 = __builtin_amdgcn_mfma_f32_16x16x32_f16(__builtin_bit_cast(f16x8, W), Bf, C0, 0, 0, 0);
        W = (u32x4v){ pk2(ev2(pa[0],ta[0],k1a[0],x1), ev2(pa[1],ta[1],k1a[1],x1)),
                      pk2(ev2(pa[2],ta[2],k1a[2],x1), ev2(pa[3],ta[3],k1a[3],x1)),
                      pk2(ev2(pb[0],tb[0],k1b[0],x1), ev2(pb[1],tb[1],k1b[1],x1)),
                      pk2(ev2(pb[2],tb[2],k1b[2],x1), ev2(pb[3],tb[3],k1b[3],x1)) };
        C1 = __builtin_amdgcn_mfma_f32_16x16x32_f16(__builtin_bit_cast(f16x8, W), Bf, C1, 0, 0, 0);
        W = (u32x4v){ pk2(ev2(pa[0],ta[0],k2a[0],x2), ev2(pa[1],ta[1],k2a[1],x2)),
                      pk2(ev2(pa[2],ta[2],k2a[2],x2), ev2(pa[3],ta[3],k2a[3],x2)),
                      pk2(ev2(pb[0],tb[0],k2b[0],x2), ev2(pb[1],tb[1],k2b[1],x2)),
                      pk2(ev2(pb[2],tb[2],k2b[2],x2), ev2(pb[3],tb[3],k2b[3],x2)) };
        C2 = __builtin_amdgcn_mfma_f32_16x16x32_f16(__builtin_bit_cast(f16x8, W), Bf, C2, 0, 0, 0);
        W = (u32x4v){ pk2(ev2(pa[0],ta[0],k3a[0],x3), ev2(pa[1],ta[1],k3a[1],x3)),
                      pk2(ev2(pa[2],ta[2],k3a[2],x3), ev2(pa[3],ta[3],k3a[3],x3)),
                      pk2(ev2(pb[0],tb[0],k3b[0],x3), ev2(pb[1],tb[1],k3b[1],x3)),
                      pk2(ev2(pb[2],tb[2],k3b[2],x3), ev2(pb[3],tb[3],k3b[3],x3)) };
        C3 = __builtin_amdgcn_mfma_f32_16x16x32_f16(__builtin_bit_cast(f16x8, W), Bf, C3, 0, 0, 0);
    }

    // ---- epilogue: per-pixel sum over the 4 n-chunks (shared Mq) ----
    if (col < 4) {
        float* pcf = (float*)pc4;
        #pragma unroll
        for (int i = 0; i < 4; ++i) {        // C layout: col=ch, row=4g+i
            int r0 = 4*g + i;
            pcf[(wave*64 + r0     )*4 + col] = C0[i];
            pcf[(wave*64 + r0 + 16)*4 + col] = C1[i];
            pcf[(wave*64 + r0 + 32)*4 + col] = C2[i];
            pcf[(wave*64 + r0 + 48)*4 + col] = C3[i];
        }
    }
    __syncthreads();
    if (tid < 256) {
        int px = tid;
        int pq = px >> 6, l = px & 63;
        f32x4 S = pc4[4*pq+0][l] + pc4[4*pq+1][l] + pc4[4*pq+2][l] + pc4[4*pq+3][l];
        float inv = 1.0f / (S[0] + 1e-6f);   // S: (alpha, r, g, b)
        int o = (row*256 + px) * 3;
        out[o] = S[1]*inv; out[o+1] = S[2]*inv; out[o+2] = S[3]*inv;
    }
}

extern "C" void kernel_launch(void* const* d_in, const int* in_sizes, int n_in,
                              void* d_out, int out_size, void* d_ws, size_t ws_size,
                              hipStream_t stream) {
    const float* rho    = (const float*)d_in[0];
    const float* sigma  = (const float*)d_in[1];
    const float* coords = (const float*)d_in[2];
    const float* alpha  = (const float*)d_in[3];
    const float* colors = (const float*)d_in[4];
    float* out = (float*)d_out;   // xy derived analytically (validated r8)

    // 256 rows -> 256 blocks x 1024 threads = exactly 1 block/CU
    splat_fused<<<256, 1024, 0, stream>>>(rho, sigma, coords, alpha, colors, out);
}

// Round 13
// 18.059 us; speedup vs baseline: 3.1885x; 1.1385x over previous
//
#include <hip/hip_runtime.h>
#include <math.h>

#define NN    1000
#define NPAD  1024
#define NTILE 32              /* 32 n-tiles of 32 gaussians                 */
#define TPW   8               /* tiles per wave (4 n-chunks of 256)         */
#define LOG2E 1.4426950408889634f
#define LOG2_2PI 2.6514961294723187f   /* log2(2*pi) */

typedef float        f32x4  __attribute__((ext_vector_type(4)));
typedef _Float16     f16x8  __attribute__((ext_vector_type(8)));
typedef unsigned int u32x4v __attribute__((ext_vector_type(4)));

static __device__ __forceinline__ float ex2(float x)  { return __builtin_amdgcn_exp2f(x); }
static __device__ __forceinline__ float lg2(float x)  { return __builtin_amdgcn_logf(x); }
static __device__ __forceinline__ float rcp_(float x) { return __builtin_amdgcn_rcpf(x); }
// native sigmoid / tanh (1-ulp-class; output path is f16 so plenty accurate)
static __device__ __forceinline__ float fsig(float x) { return rcp_(1.f + ex2(-LOG2E * x)); }
// tanh(x) = 1 - 2/(exp2(2*log2e*x)+1)
static __device__ __forceinline__ float ftanh2x(float two_x_log2e) {  // pass 2*log2e*x
    return 1.f - 2.f * rcp_(ex2(two_x_log2e) + 1.f);
}
// e = exp2(K - u^2), u = p*x + t   (2 FMA + exp2; NO max subtraction)
static __device__ __forceinline__ float ev2(float p, float t, float K, float x) {
    float u = fmaf(p, x, t);
    return ex2(fmaf(-u, u, K));
}
static __device__ __forceinline__ unsigned pk2(float a, float b) {
    return __builtin_bit_cast(unsigned, __builtin_amdgcn_cvt_pkrtz(a, b));
}

// ============ fused kernel: ONE IMAGE ROW per block (256 px, 16 waves) =====
// phase 0a: 1 gaussian/thread -> row-folded params (p, t, K') to LDS
// phase 0b: B-fragments (sigmoid alpha|rgb -> f16)
// phase 0c: per-16px-group analytic max bound (epilogue EPS term ONLY)
// pass C:   raw e = exp2(K' - u^2), f16 MFMA accumulate (alpha,r,g,b)
// epilogue: out = C_rgb / (C_alpha + EPS * 2^Mq)
__global__ __launch_bounds__(1024, 4) void splat_fused(
    const float* __restrict__ rho, const float* __restrict__ sigma,
    const float* __restrict__ coords, const float* __restrict__ alpha,
    const float* __restrict__ colors, float* __restrict__ out)
{
    __shared__ f32x4  Lp4[NPAD/4], Lt4[NPAD/4], Lk4[NPAD/4];  // 12 KB
    __shared__ u32x4v Lbf[NTILE][4][4];                       //  8 KB
    __shared__ float  pm2[64][16];                            //  4 KB
    __shared__ float  pmg[16];
    __shared__ f32x4  pc4[16][64];                            // 16 KB

    const int tid  = threadIdx.x;
    const int wave = tid >> 6, lane = tid & 63;
    const int col  = lane & 15, g = lane >> 4;
    const int nchunk = wave & 3, pxq = wave >> 2;   // n-chunk x pixel-quad
    const int row  = blockIdx.x;
    const float step = 2.0f / 255.0f;
    const float y  = -1.0f + (float)row * step;                 // block-uniform
    const float xb = -1.0f + (float)(64*pxq + col) * step;
    const float x0 = xb, x1 = xb + 16.f*step, x2 = xb + 32.f*step, x3 = xb + 48.f*step;

    // ---- phase 0a: one gaussian per thread (native transcendentals) ----
    float* Lp = (float*)Lp4; float* Lt = (float*)Lt4; float* Lk = (float*)Lk4;
    {
        const int n = tid;
        float p, q, r_, u0, v0, K;
        if (n >= NN) { p=q=r_=u0=v0=0.f; K=-1e30f; }   // dummy: contributes 0
        else {
            float sx = ftanh2x(LOG2E * sigma[2*n])   + 1e-4f;  // tanh(s/2)
            float sy = ftanh2x(LOG2E * sigma[2*n+1]) + 1e-4f;
            float ra = fsig(rho[n]) + 1e-6f;
            float cxx = sx*sx + 1e-6f, cyy = sy*sy + 1e-6f;
            float cxy = sx*sy*ra;
            float det = cxx*cyy - cxy*cxy;
            float invdet = rcp_(det);
            float hl = 0.5f * LOG2E;
            p  = sqrtf(hl * cyy * invdet);
            q  = (-hl * cxy * invdet) * rcp_(p);
            r_ = sqrtf(hl * rcp_(cyy));      // exact: b - q^2 = hl/cyy
            float cx = ftanh2x((2.f*LOG2E) * coords[2*n])   - 0.5f;
            float cy = ftanh2x((2.f*LOG2E) * coords[2*n+1]) - 0.5f;
            u0 = p*cx + q*cy;
            v0 = r_*cy;
            K  = 0.5f * lg2(det + 1e-6f) - LOG2_2PI;
        }
        float t = fmaf(q, y, u0);
        float v = fmaf(r_, y, v0);
        Lp[tid] = p; Lt[tid] = t; Lk[tid] = fmaf(-v, v, K);
    }
    // ---- phase 0b: B-fragments, one slot per thread (tid < 512) ----
    if (tid < 512) {                         // slot: T(32) x c(4) x g2(4)
        int T = tid >> 4, c = (tid >> 2) & 3, g2 = tid & 3;
        unsigned w[4] = {0u,0u,0u,0u};
        #pragma unroll
        for (int j = 0; j < 8; ++j) {
            int n = T*32 + g2*8 + j;
            float act = 0.f;
            if (n < NN)
                act = fsig((c == 0) ? alpha[n] : colors[3*n + c - 1]);
            unsigned short us = __builtin_bit_cast(unsigned short, (_Float16)act);
            w[j>>1] |= (unsigned)us << (16*(j&1));
        }
        Lbf[T][c][g2] = (u32x4v){w[0], w[1], w[2], w[3]};
    }
    __syncthreads();

    // preload this wave's B-fragments (n-chunk owns tiles nchunk*8 .. +7)
    u32x4v BfR[TPW];
    #pragma unroll
    for (int t = 0; t < TPW; ++t)
        BfR[t] = (col < 4) ? Lbf[nchunk*TPW + t][col][g] : (u32x4v){0u,0u,0u,0u};

    // ---- phase 0c: analytic group-max. thread = (16-g chunk) x (16px group) ----
    // max_{x in [xlo,xhi]} (K' - (p*x+t)^2) = K' - (ulo*uhi>0 ? min(ulo^2,uhi^2) : 0)
    {
        const int q16 = tid & 15, chunk = tid >> 4;
        const float xlo = -1.0f + (float)(16*q16) * step;
        const float xhi = xlo + 15.f*step;
        const int nb = chunk * 16;
        float mx = -3.0e38f;
        #pragma unroll
        for (int i = 0; i < 16; ++i) {
            float p = Lp[nb+i], t = Lt[nb+i], Kp = Lk[nb+i];
            float ulo = fmaf(p, xlo, t);
            float uhi = fmaf(p, xhi, t);
            float pen = (ulo*uhi > 0.f) ? fminf(ulo*ulo, uhi*uhi) : 0.f;
            mx = fmaxf(mx, Kp - pen);
        }
        pm2[chunk][q16] = mx;
    }
    __syncthreads();
    if (tid < 16) {                          // stage 2: 64 partials -> EPS term
        float M = -3.0e38f;
        #pragma unroll
        for (int j = 0; j < 64; ++j) M = fmaxf(M, pm2[j][tid]);
        pmg[tid] = 1e-6f * ex2(M);           // EPS * 2^Mq  (ref-equivalent EPS)
    }
    // (no barrier needed before pass C: pass C doesn't read pmg; the
    //  pc4 barrier below orders pmg for the epilogue.)

    const int nbase = nchunk*256 + g*8;

    // ---- pass C: raw e = exp2(K' - u^2), MFMA accumulate (alpha,r,g,b) ----
    f32x4 C0 = {0.f,0.f,0.f,0.f}, C1 = {0.f,0.f,0.f,0.f};
    f32x4 C2 = {0.f,0.f,0.f,0.f}, C3 = {0.f,0.f,0.f,0.f};
    for (int t = 0; t < TPW; ++t) {
        int q4 = (nbase + t*32) >> 2;
        f32x4 pa = Lp4[q4], pb = Lp4[q4+1];
        f32x4 ta = Lt4[q4], tb = Lt4[q4+1];
        f32x4 ka = Lk4[q4], kb = Lk4[q4+1];
        f16x8 Bf = __builtin_bit_cast(f16x8, BfR[t]);

        u32x4v W;
        W = (u32x4v){ pk2(ev2(pa[0],ta[0],ka[0],x0), ev2(pa[1],ta[1],ka[1],x0)),
                      pk2(ev2(pa[2],ta[2],ka[2],x0), ev2(pa[3],ta[3],ka[3],x0)),
                      pk2(ev2(pb[0],tb[0],kb[0],x0), ev2(pb[1],tb[1],kb[1],x0)),
                      pk2(ev2(pb[2],tb[2],kb[2],x0), ev2(pb[3],tb[3],kb[3],x0)) };
        C0 = __builtin_amdgcn_mfma_f32_16x16x32_f16(__builtin_bit_cast(f16x8, W), Bf, C0, 0, 0, 0);
        W = (u32x4v){ pk2(ev2(pa[0],ta[0],ka[0],x1), ev2(pa[1],ta[1],ka[1],x1)),
                      pk2(ev2(pa[2],ta[2],ka[2],x1), ev2(pa[3],ta[3],ka[3],x1)),
                      pk2(ev2(pb[0],tb[0],kb[0],x1), ev2(pb[1],tb[1],kb[1],x1)),
                      pk2(ev2(pb[2],tb[2],kb[2],x1), ev2(pb[3],tb[3],kb[3],x1)) };
        C1 = __builtin_amdgcn_mfma_f32_16x16x32_f16(__builtin_bit_cast(f16x8, W), Bf, C1, 0, 0, 0);
        W = (u32x4v){ pk2(ev2(pa[0],ta[0],ka[0],x2), ev2(pa[1],ta[1],ka[1],x2)),
                      pk2(ev2(pa[2],ta[2],ka[2],x2), ev2(pa[3],ta[3],ka[3],x2)),
                      pk2(ev2(pb[0],tb[0],kb[0],x2), ev2(pb[1],tb[1],kb[1],x2)),
                      pk2(ev2(pb[2],tb[2],kb[2],x2), ev2(pb[3],tb[3],kb[3],x2)) };
        C2 = __builtin_amdgcn_mfma_f32_16x16x32_f16(__builtin_bit_cast(f16x8, W), Bf, C2, 0, 0, 0);
        W = (u32x4v){ pk2(ev2(pa[0],ta[0],ka[0],x3), ev2(pa[1],ta[1],ka[1],x3)),
                      pk2(ev2(pa[2],ta[2],ka[2],x3), ev2(pa[3],ta[3],ka[3],x3)),
                      pk2(ev2(pb[0],tb[0],kb[0],x3), ev2(pb[1],tb[1],kb[1],x3)),
                      pk2(ev2(pb[2],tb[2],kb[2],x3), ev2(pb[3],tb[3],kb[3],x3)) };
        C3 = __builtin_amdgcn_mfma_f32_16x16x32_f16(__builtin_bit_cast(f16x8, W), Bf, C3, 0, 0, 0);
    }

    // ---- epilogue: per-pixel sum over the 4 n-chunks ----
    if (col < 4) {
        float* pcf = (float*)pc4;
        #pragma unroll
        for (int i = 0; i < 4; ++i) {        // C layout: col=ch, row=4g+i
            int r0 = 4*g + i;
            pcf[(wave*64 + r0     )*4 + col] = C0[i];
            pcf[(wave*64 + r0 + 16)*4 + col] = C1[i];
            pcf[(wave*64 + r0 + 32)*4 + col] = C2[i];
            pcf[(wave*64 + r0 + 48)*4 + col] = C3[i];
        }
    }
    __syncthreads();
    if (tid < 256) {
        int px = tid;
        int pq = px >> 6, l = px & 63;
        f32x4 S = pc4[4*pq+0][l] + pc4[4*pq+1][l] + pc4[4*pq+2][l] + pc4[4*pq+3][l];
        float inv = 1.0f / (S[0] + pmg[px >> 4]);   // S: (alpha, r, g, b)
        int o = (row*256 + px) * 3;
        out[o] = S[1]*inv; out[o+1] = S[2]*inv; out[o+2] = S[3]*inv;
    }
}

extern "C" void kernel_launch(void* const* d_in, const int* in_sizes, int n_in,
                              void* d_out, int out_size, void* d_ws, size_t ws_size,
                              hipStream_t stream) {
    const float* rho    = (const float*)d_in[0];
    const float* sigma  = (const float*)d_in[1];
    const float* coords = (const float*)d_in[2];
    const float* alpha  = (const float*)d_in[3];
    const float* colors = (const float*)d_in[4];
    float* out = (float*)d_out;   // xy derived analytically (validated r8)

    // 256 rows -> 256 blocks x 1024 threads = exactly 1 block/CU
    splat_fused<<<256, 1024, 0, stream>>>(rho, sigma, coords, alpha, colors, out);
}